// Round 15
// baseline (814.648 us; speedup 1.0000x reference)
//
#include <hip/hip_runtime.h>
#include <math.h>

typedef float f32x4 __attribute__((ext_vector_type(4)));
typedef unsigned short u16x8 __attribute__((ext_vector_type(8)));
typedef unsigned short u16x4 __attribute__((ext_vector_type(4)));
typedef __bf16 bf16x8 __attribute__((ext_vector_type(8)));
typedef unsigned int u32;

#define DEV static __device__ __forceinline__

DEV unsigned short f2bf(float f) {            // native cast -> v_cvt_pk_bf16_f32 (m240)
  __bf16 h = (__bf16)f;
  return __builtin_bit_cast(unsigned short, h);
}
DEV float bf2f(unsigned short s) { return __uint_as_float(((unsigned)s) << 16); }
DEV bf16x8 asbf(u16x8 v) { return __builtin_bit_cast(bf16x8, v); }

DEV void gload16(const void* g, void* l) {    // async global->LDS, 16B/lane, wave-uniform LDS base
  __builtin_amdgcn_global_load_lds((const __attribute__((address_space(1))) u32*)g,
                                   (__attribute__((address_space(3))) u32*)l, 16, 0, 0);
}

// ---------------------------------------------------------------- f32 -> bf16 bulk convert
__global__ void cvt_kernel(const float* __restrict__ in, unsigned short* __restrict__ out, int n8) {
  for (int i = blockIdx.x * 256 + threadIdx.x; i < n8; i += gridDim.x * 256) {
    const float* s = in + (size_t)i * 8;
    f32x4 a = *(const f32x4*)s, b = *(const f32x4*)(s + 4);
    u16x8 o;
    for (int j = 0; j < 4; ++j) { o[j] = f2bf(a[j]); o[j + 4] = f2bf(b[j]); }
    *(u16x8*)(out + (size_t)i * 8) = o;
  }
}

// two-segment convert (wo + w1 in one dispatch)
__global__ void cvt2_kernel(const float* __restrict__ s0, unsigned short* __restrict__ d0, int na,
                            const float* __restrict__ s1, unsigned short* __restrict__ d1, int nb) {
  int total = na + nb;
  for (int i = blockIdx.x * 256 + threadIdx.x; i < total; i += gridDim.x * 256) {
    const float* s; unsigned short* d; int k;
    if (i < na) { s = s0; d = d0; k = i; } else { s = s1; d = d1; k = i - na; }
    f32x4 a = *(const f32x4*)(s + (size_t)k * 8), b = *(const f32x4*)(s + (size_t)k * 8 + 4);
    u16x8 o;
    for (int j = 0; j < 4; ++j) { o[j] = f2bf(a[j]); o[j + 4] = f2bf(b[j]); }
    *(u16x8*)(d + (size_t)k * 8) = o;
  }
}

// three-segment convert (all qkv weights, one dispatch; each segment n8=2048)
__global__ void cvt3q_kernel(const float* __restrict__ s0, unsigned short* __restrict__ d0,
                             const float* __restrict__ s1, unsigned short* __restrict__ d1,
                             const float* __restrict__ s2, unsigned short* __restrict__ d2) {
  int i = blockIdx.x * 256 + threadIdx.x;
  if (i >= 6144) return;
  const float* s; unsigned short* d; int k = i & 2047;
  int seg = i >> 11;
  s = (seg == 0) ? s0 : (seg == 1) ? s1 : s2;
  d = (seg == 0) ? d0 : (seg == 1) ? d1 : d2;
  f32x4 a = *(const f32x4*)(s + (size_t)k * 8), b = *(const f32x4*)(s + (size_t)k * 8 + 4);
  u16x8 o;
  for (int j = 0; j < 4; ++j) { o[j] = f2bf(a[j]); o[j + 4] = f2bf(b[j]); }
  *(u16x8*)(d + (size_t)k * 8) = o;
}

// ---------------------------------------------------------------- embed
__global__ void embed_kernel(const int* __restrict__ x, const float* __restrict__ tok,
                             const float* __restrict__ pos, float* __restrict__ h,
                             unsigned short* __restrict__ hbf) {
  int t = blockIdx.x, tid = threadIdx.x;
  int v = x[t], s = t & 1023;                 // S = 1024
  f32x4 a = *(const f32x4*)(tok + (size_t)v * 1024 + tid * 4);
  f32x4 b = *(const f32x4*)(pos + (size_t)s * 1024 + tid * 4);
  f32x4 r = a + b;
  *(f32x4*)(h + (size_t)t * 1024 + tid * 4) = r;
  u16x4 rb;
  for (int i = 0; i < 4; ++i) rb[i] = f2bf(r[i]);
  *(u16x4*)(hbf + (size_t)t * 1024 + tid * 4) = rb;
}

// ---------------------------------------------------------------- LayerNorm(preA + preB + res)
__global__ __launch_bounds__(256) void ln_kernel(const float* __restrict__ preA,
    const float* __restrict__ preB, const float* __restrict__ res,
    const float* __restrict__ g, const float* __restrict__ bta,
    float* __restrict__ outf, unsigned short* __restrict__ outbf) {
  int row = blockIdx.x, tid = threadIdx.x;
  size_t base = (size_t)row * 1024 + tid * 4;
  f32x4 xv = *(const f32x4*)(preA + base);
  xv += *(const f32x4*)(preB + base);
  xv += *(const f32x4*)(res + base);
  float s = xv[0] + xv[1] + xv[2] + xv[3];
  float s2 = xv[0]*xv[0] + xv[1]*xv[1] + xv[2]*xv[2] + xv[3]*xv[3];
  for (int m = 1; m < 64; m <<= 1) { s += __shfl_xor(s, m); s2 += __shfl_xor(s2, m); }
  __shared__ float red[8];
  int w = tid >> 6;
  if ((tid & 63) == 0) { red[w * 2] = s; red[w * 2 + 1] = s2; }
  __syncthreads();
  s = red[0] + red[2] + red[4] + red[6];
  s2 = red[1] + red[3] + red[5] + red[7];
  float mu = s * (1.f / 1024.f);
  float var = s2 * (1.f / 1024.f) - mu * mu;
  float rs = rsqrtf(var + 1e-5f);
  f32x4 gv = *(const f32x4*)(g + tid * 4);
  f32x4 bv = *(const f32x4*)(bta + tid * 4);
  f32x4 o; u16x4 ob;
  for (int i = 0; i < 4; ++i) { o[i] = (xv[i] - mu) * rs * gv[i] + bv[i]; ob[i] = f2bf(o[i]); }
  *(f32x4*)(outf + base) = o;
  *(u16x4*)(outbf + base) = ob;
}

// ---------------------------------------------------------------- QKV via MFMA + fused V-transpose
__global__ __launch_bounds__(256) void qkvt_kernel(const unsigned short* __restrict__ hbf,
    const unsigned short* __restrict__ wqb, const unsigned short* __restrict__ wkb,
    const unsigned short* __restrict__ wvb,
    unsigned short* __restrict__ q, unsigned short* __restrict__ k,
    unsigned short* __restrict__ vt) {
  __shared__ unsigned short T[64 * 72];
  int tid = threadIdx.x, ln = tid & 63, w = tid >> 6;
  int l15 = ln & 15, lg = ln >> 4;
  int st = blockIdx.x, hh = blockIdx.y;
  int t0 = st * 64 + w * 16;                  // token base (t = b*1024+s flattened)
  const unsigned short* xp = hbf + (size_t)(t0 + l15) * 1024 + hh * 64 + lg * 8;
  bf16x8 xa0 = asbf(*(const u16x8*)xp);
  bf16x8 xa1 = asbf(*(const u16x8*)(xp + 32));
  const unsigned short* wp[3] = {wqb, wkb, wvb};
  f32x4 acc[3][4] = {};
#pragma unroll
  for (int m = 0; m < 3; ++m) {
    __builtin_amdgcn_s_setprio(1);
#pragma unroll
    for (int ni = 0; ni < 4; ++ni) {
      const unsigned short* wb = wp[m] + (size_t)(ni * 16 + l15) * 64 + lg * 8;
      bf16x8 w0 = asbf(*(const u16x8*)wb);
      bf16x8 w1 = asbf(*(const u16x8*)(wb + 32));
      acc[m][ni] = __builtin_amdgcn_mfma_f32_16x16x32_bf16(xa0, w0, acc[m][ni], 0, 0, 0);
      acc[m][ni] = __builtin_amdgcn_mfma_f32_16x16x32_bf16(xa1, w1, acc[m][ni], 0, 0, 0);
    }
    __builtin_amdgcn_s_setprio(0);
  }
  unsigned short* outp[2] = {q, k};
#pragma unroll
  for (int m = 0; m < 2; ++m)
#pragma unroll
    for (int ni = 0; ni < 4; ++ni)
#pragma unroll
      for (int r = 0; r < 4; ++r)
        outp[m][(size_t)(t0 + 4 * lg + r) * 1024 + hh * 64 + ni * 16 + l15] = f2bf(acc[m][ni][r]);
#pragma unroll
  for (int ni = 0; ni < 4; ++ni)
#pragma unroll
    for (int r = 0; r < 4; ++r)
      T[(ni * 16 + l15) * 72 + (w * 16 + 4 * lg + r)] = f2bf(acc[2][ni][r]);
  __syncthreads();
  int b = st >> 4, sb = (st & 15) * 64;
#pragma unroll
  for (int j = 0; j < 2; ++j) {
    int idx = tid + 256 * j; int e = idx >> 3, s8 = (idx & 7) * 8;
    *(u16x8*)(vt + ((size_t)((b * 16 + hh) * 64 + e)) * 1024 + sb + s8) =
        *(const u16x8*)&T[e * 72 + s8];
  }
}

// ---------------------------------------------------------------- flash attention, KVBLK=128, T13+T14+T5
__global__ __launch_bounds__(256, 2) void attn_kernel(const unsigned short* __restrict__ qb,
    const unsigned short* __restrict__ kb, const unsigned short* __restrict__ vtb,
    unsigned short* __restrict__ ob) {
  constexpr int PK = 72, PV = 136, PP = 136;
  __shared__ unsigned short Ks[128 * PK], Vs[64 * PV], Ps[4][16 * PP];
  int tid = threadIdx.x, lane = tid & 63, w = tid >> 6;
  int l15 = lane & 15, lg = lane >> 4;
  int qt = blockIdx.x, bh = blockIdx.y, b = bh >> 4, hh = bh & 15;
  int q0 = qt * 64 + w * 16;
  const unsigned short* qrow = qb + ((size_t)(b * 1024 + q0 + l15) * 16 + hh) * 64 + lg * 8;
  bf16x8 qa0 = asbf(*(const u16x8*)qrow);
  bf16x8 qa1 = asbf(*(const u16x8*)(qrow + 32));
  {                                            // pre-scale Q by 1/32 (exact power-of-2)
    const __bf16 s = (__bf16)0.03125f;
#pragma unroll
    for (int i = 0; i < 8; ++i) { qa0[i] = qa0[i] * s; qa1[i] = qa1[i] * s; }
  }
  float m_[4] = {-1e30f, -1e30f, -1e30f, -1e30f};
  float ls[4] = {0.f, 0.f, 0.f, 0.f};
  f32x4 oacc[4] = {};

  u16x8 KR[4], VR[4];                         // T14: reg-staged next tile
  auto loadT = [&](int kt) {
#pragma unroll
    for (int j = 0; j < 4; ++j) {
      int idx = tid + 256 * j;
      int r = idx >> 3, c0 = (idx & 7) * 8;
      KR[j] = *(const u16x8*)(kb + ((size_t)(b * 1024 + kt * 128 + r) * 16 + hh) * 64 + c0);
      int rv = idx >> 4, cv = (idx & 15) * 8;
      VR[j] = *(const u16x8*)(vtb + ((size_t)((b * 16 + hh) * 64) + rv) * 1024 + kt * 128 + cv);
    }
  };
  auto writeT = [&]() {
#pragma unroll
    for (int j = 0; j < 4; ++j) {
      int idx = tid + 256 * j;
      int r = idx >> 3, c0 = (idx & 7) * 8;
      *(u16x8*)(&Ks[r * PK + c0]) = KR[j];
      int rv = idx >> 4, cv = (idx & 15) * 8;
      *(u16x8*)(&Vs[rv * PV + cv]) = VR[j];
    }
  };
  loadT(0); writeT();
  __syncthreads();

  for (int kt = 0; kt < 8; ++kt) {
    f32x4 sf[8] = {};
    __builtin_amdgcn_s_setprio(1);
#pragma unroll
    for (int n = 0; n < 8; ++n) {
      bf16x8 k0 = asbf(*(const u16x8*)(&Ks[(n * 16 + l15) * PK + lg * 8]));
      bf16x8 k1 = asbf(*(const u16x8*)(&Ks[(n * 16 + l15) * PK + 32 + lg * 8]));
      sf[n] = __builtin_amdgcn_mfma_f32_16x16x32_bf16(qa0, k0, sf[n], 0, 0, 0);
      sf[n] = __builtin_amdgcn_mfma_f32_16x16x32_bf16(qa1, k1, sf[n], 0, 0, 0);
    }
    __builtin_amdgcn_s_setprio(0);
    if (kt < 7) loadT(kt + 1);                // issue-early: latency hides under softmax+PV
    float tm[4];
#pragma unroll
    for (int r = 0; r < 4; ++r) {
      float t0 = fmaxf(fmaxf(fmaxf(sf[0][r], sf[1][r]), fmaxf(sf[2][r], sf[3][r])),
                       fmaxf(fmaxf(sf[4][r], sf[5][r]), fmaxf(sf[6][r], sf[7][r])));
      for (int msk = 1; msk < 16; msk <<= 1) t0 = fmaxf(t0, __shfl_xor(t0, msk));
      tm[r] = t0;
    }
    bool need = false;
#pragma unroll
    for (int r = 0; r < 4; ++r) need |= (tm[r] > m_[r] + 8.f);
    if (__any(need)) {
#pragma unroll
      for (int r = 0; r < 4; ++r) {
        float nm = fmaxf(m_[r], tm[r]);
        float sc = __expf(m_[r] - nm);
        ls[r] *= sc;
#pragma unroll
        for (int n = 0; n < 4; ++n) oacc[n][r] *= sc;
        m_[r] = nm;
      }
    }
    float rsum[4] = {0.f, 0.f, 0.f, 0.f};
    unsigned short pb[8][4];
#pragma unroll
    for (int n = 0; n < 8; ++n)
#pragma unroll
      for (int r = 0; r < 4; ++r) {
        float pv = __expf(sf[n][r] - m_[r]);
        rsum[r] += pv;
        pb[n][r] = f2bf(pv);
      }
#pragma unroll
    for (int r = 0; r < 4; ++r) {
      float t0 = rsum[r];
      for (int msk = 1; msk < 16; msk <<= 1) t0 += __shfl_xor(t0, msk);
      ls[r] += t0;
    }
    unsigned short* pw = Ps[w];                // per-wave region: no block barrier needed
#pragma unroll
    for (int n = 0; n < 8; ++n)
#pragma unroll
      for (int r = 0; r < 4; ++r)
        pw[(4 * lg + r) * PP + n * 16 + l15] = pb[n][r];
    asm volatile("s_waitcnt lgkmcnt(0)" ::: "memory");
    __builtin_amdgcn_sched_barrier(0);
    bf16x8 pa[4];
#pragma unroll
    for (int ks = 0; ks < 4; ++ks)
      pa[ks] = asbf(*(const u16x8*)(&pw[l15 * PP + ks * 32 + lg * 8]));
    __builtin_amdgcn_s_setprio(1);
#pragma unroll
    for (int n = 0; n < 4; ++n) {
#pragma unroll
      for (int ks = 0; ks < 4; ++ks) {
        bf16x8 v0 = asbf(*(const u16x8*)(&Vs[(n * 16 + l15) * PV + ks * 32 + lg * 8]));
        oacc[n] = __builtin_amdgcn_mfma_f32_16x16x32_bf16(pa[ks], v0, oacc[n], 0, 0, 0);
      }
    }
    __builtin_amdgcn_s_setprio(0);
    __syncthreads();
    if (kt < 7) { writeT(); __syncthreads(); }
  }
#pragma unroll
  for (int n = 0; n < 4; ++n)
#pragma unroll
    for (int r = 0; r < 4; ++r) {
      float o = oacc[n][r] / ls[r];
      ob[((size_t)(b * 1024 + q0 + 4 * lg + r) * 16 + hh) * 64 + n * 16 + l15] = f2bf(o);
    }
}

// ---------------------------------------------------------------- wo/FFN2: 64x256 2-phase counted GEMM, split-K=2
// Cf[kh] = A @ B^T (+bias if kh==0), f32 out [2048,1024]. grid = 256 (32 mt x 4 nt x 2 kh), 512 thr.
// LDS 81920 B: A[2][64][64] @0, B[2][256][64] @8192. B rows permuted p = f*128+wn*16+l15.
// Ledger (5 gloads/tile: P1{A,Bg0,Bg1}, P2{Bg2,Bg3}): close P1 vmcnt(3), close P2 vmcnt(2).
__global__ __launch_bounds__(512, 2) void gemmF2_kernel(
    const unsigned short* __restrict__ A, int lda,
    const unsigned short* __restrict__ B, int ldb,
    const float* __restrict__ bias,
    float* __restrict__ CfA, float* __restrict__ CfB, int Ksub) {
  extern __shared__ unsigned short sm[];
  int b = blockIdx.x;
  int c = (int)gridDim.x >> 3;
  int wg = (b & 7) * c + (b >> 3);            // XCD-contiguous (grid % 8 == 0)
  int mt = wg & 31, nt = (wg >> 5) & 3, kh = wg >> 7;
  int m0 = mt * 64, n0 = nt * 256;
  const unsigned short* Ae = A + (size_t)kh * Ksub;
  const unsigned short* Be = B + (size_t)kh * Ksub;

  int tid = threadIdx.x, ln = tid & 63, wv = tid >> 6;
  int l15 = ln & 15, lg = ln >> 4;
  int wn = wv;                                // 8 N-waves, cols wn*32
  int l7 = l15 & 7;

  int srow = tid >> 3, sblk = (tid & 7) ^ (srow & 7);
  const unsigned short* Ab = Ae + (size_t)(m0 + srow) * lda + sblk * 8;
  const unsigned short* BbG[4];
#pragma unroll
  for (int g = 0; g < 4; ++g) {
    int p = g * 64 + srow;
    int f = p >> 7, wnn = (p >> 4) & 7;
    int r = wnn * 32 + f * 16 + (p & 15);     // inverse row permutation
    BbG[g] = Be + (size_t)(n0 + r) * ldb + sblk * 8;
  }
  auto stA = [&](int e, int k0) {
    gload16(Ab + k0, &sm[e * 4096 + wv * 512]);
  };
  auto stB = [&](int e, int g, int k0) {
    gload16(BbG[g] + k0, &sm[8192 + e * 16384 + g * 4096 + wv * 512]);
  };
  auto ldsA = [&](int d, int mi, int ks) -> bf16x8 {
    int row = mi * 16 + l15;
    return asbf(*(const u16x8*)&sm[d * 4096 + row * 64 + (((ks << 2) | lg) ^ l7) * 8]);
  };
  auto ldsB = [&](int d, int f, int ks) -> bf16x8 {
    int p = f * 128 + wn * 16 + l15;          // permuted row
    return asbf(*(const u16x8*)&sm[8192 + d * 16384 + p * 64 + (((ks << 2) | lg) ^ l7) * 8]);
  };

  f32x4 acc[4][2] = {};
  bf16x8 Af[4][2], Bf0[2], Bf1[2];

#define PH_OPEN() __builtin_amdgcn_s_barrier(); \
  asm volatile("s_waitcnt lgkmcnt(0)" ::: "memory"); \
  __builtin_amdgcn_sched_barrier(0); __builtin_amdgcn_s_setprio(1)

  stA(0, 0); stB(0, 0, 0); stB(0, 1, 0); stB(0, 2, 0); stB(0, 3, 0);
  asm volatile("s_waitcnt vmcnt(2)" ::: "memory");
  __builtin_amdgcn_s_barrier();

  int ntk = Ksub >> 6;
  for (int kk = 0; kk < ntk; ++kk) {
    int d = kk & 1, e = d ^ 1, k1 = (kk + 1) << 6;
    bool pf = (kk + 1 < ntk);
    { // P1
      Bf0[0] = ldsB(d, 0, 0); Bf0[1] = ldsB(d, 0, 1);
#pragma unroll
      for (int mi = 0; mi < 4; ++mi) { Af[mi][0] = ldsA(d, mi, 0); Af[mi][1] = ldsA(d, mi, 1); }
      if (pf) { stA(e, k1); stB(e, 0, k1); stB(e, 1, k1); }
      PH_OPEN();
#pragma unroll
      for (int mi = 0; mi < 4; ++mi) {
        acc[mi][0] = __builtin_amdgcn_mfma_f32_16x16x32_bf16(Af[mi][0], Bf0[0], acc[mi][0], 0, 0, 0);
        acc[mi][0] = __builtin_amdgcn_mfma_f32_16x16x32_bf16(Af[mi][1], Bf0[1], acc[mi][0], 0, 0, 0);
      }
      __builtin_amdgcn_s_setprio(0);
      if (pf) { asm volatile("s_waitcnt vmcnt(3)" ::: "memory"); }
      else    { asm volatile("s_waitcnt vmcnt(0)" ::: "memory"); }
      __builtin_amdgcn_s_barrier();
    }
    { // P2
      Bf1[0] = ldsB(d, 1, 0); Bf1[1] = ldsB(d, 1, 1);
      if (pf) { stB(e, 2, k1); stB(e, 3, k1); }
      PH_OPEN();
#pragma unroll
      for (int mi = 0; mi < 4; ++mi) {
        acc[mi][1] = __builtin_amdgcn_mfma_f32_16x16x32_bf16(Af[mi][0], Bf1[0], acc[mi][1], 0, 0, 0);
        acc[mi][1] = __builtin_amdgcn_mfma_f32_16x16x32_bf16(Af[mi][1], Bf1[1], acc[mi][1], 0, 0, 0);
      }
      __builtin_amdgcn_s_setprio(0);
      if (pf) { asm volatile("s_waitcnt vmcnt(2)" ::: "memory"); }
      __builtin_amdgcn_s_barrier();
    }
  }
#undef PH_OPEN

  float* fb = (float*)sm;
  int fbase = wv * 2048;
  float* Cf = (kh == 0) ? CfA : CfB;
  float bv[2] = {0.f, 0.f};
  if (kh == 0) { bv[0] = bias[n0 + wn * 32 + l15]; bv[1] = bias[n0 + wn * 32 + 16 + l15]; }
#pragma unroll
  for (int mi = 0; mi < 4; ++mi)
#pragma unroll
    for (int f = 0; f < 2; ++f)
#pragma unroll
      for (int r = 0; r < 4; ++r)
        fb[fbase + (mi * 16 + lg * 4 + r) * 32 + f * 16 + l15] = acc[mi][f][r] + bv[f];
  asm volatile("s_waitcnt lgkmcnt(0)" ::: "memory");
  __builtin_amdgcn_sched_barrier(0);
#pragma unroll
  for (int i = 0; i < 8; ++i) {
    int row = i * 8 + (ln >> 3);
    int col = (ln & 7) * 4;
    f32x4 v = *(const f32x4*)&fb[fbase + row * 32 + col];
    *(f32x4*)(&Cf[(size_t)(m0 + row) * 1024 + n0 + wn * 32 + col]) = v;
  }
}

// ---------------------------------------------------------------- logits: 64x256 2-phase counted GEMM, 2 blocks/CU
// C = A @ B^T + bias, f32 out [2048,ldc]. grid = 32 mt x 125 nt = 4000 (%8==0), 512 thr.
// Same structure/ledger/permutation as gemmF2, no split-K, LDS 81920 B -> exactly 2 blocks/CU.
__global__ __launch_bounds__(512, 2) void gemmL_kernel(
    const unsigned short* __restrict__ A, int lda,
    const unsigned short* __restrict__ B, int ldb,
    const float* __restrict__ bias, float* __restrict__ C, int ldc, int K) {
  extern __shared__ unsigned short sm[];
  int b = blockIdx.x;
  int c = (int)gridDim.x >> 3;
  int wg = (b & 7) * c + (b >> 3);            // XCD-contiguous (grid % 8 == 0)
  int mt = wg & 31, nt = wg >> 5;
  int m0 = mt * 64, n0 = nt * 256;

  int tid = threadIdx.x, ln = tid & 63, wv = tid >> 6;
  int l15 = ln & 15, lg = ln >> 4;
  int wn = wv;                                // 8 N-waves, cols wn*32
  int l7 = l15 & 7;

  int srow = tid >> 3, sblk = (tid & 7) ^ (srow & 7);
  const unsigned short* Ab = A + (size_t)(m0 + srow) * lda + sblk * 8;
  const unsigned short* BbG[4];
#pragma unroll
  for (int g = 0; g < 4; ++g) {
    int p = g * 64 + srow;
    int f = p >> 7, wnn = (p >> 4) & 7;
    int r = wnn * 32 + f * 16 + (p & 15);     // inverse row permutation
    BbG[g] = B + (size_t)(n0 + r) * ldb + sblk * 8;
  }
  auto stA = [&](int e, int k0) {
    gload16(Ab + k0, &sm[e * 4096 + wv * 512]);
  };
  auto stB = [&](int e, int g, int k0) {
    gload16(BbG[g] + k0, &sm[8192 + e * 16384 + g * 4096 + wv * 512]);
  };
  auto ldsA = [&](int d, int mi, int ks) -> bf16x8 {
    int row = mi * 16 + l15;
    return asbf(*(const u16x8*)&sm[d * 4096 + row * 64 + (((ks << 2) | lg) ^ l7) * 8]);
  };
  auto ldsB = [&](int d, int f, int ks) -> bf16x8 {
    int p = f * 128 + wn * 16 + l15;          // permuted row
    return asbf(*(const u16x8*)&sm[8192 + d * 16384 + p * 64 + (((ks << 2) | lg) ^ l7) * 8]);
  };

  f32x4 acc[4][2] = {};
  bf16x8 Af[4][2], Bf0[2], Bf1[2];

#define PH_OPEN() __builtin_amdgcn_s_barrier(); \
  asm volatile("s_waitcnt lgkmcnt(0)" ::: "memory"); \
  __builtin_amdgcn_sched_barrier(0); __builtin_amdgcn_s_setprio(1)

  stA(0, 0); stB(0, 0, 0); stB(0, 1, 0); stB(0, 2, 0); stB(0, 3, 0);
  asm volatile("s_waitcnt vmcnt(2)" ::: "memory");
  __builtin_amdgcn_s_barrier();

  int ntk = K >> 6;
  for (int kk = 0; kk < ntk; ++kk) {
    int d = kk & 1, e = d ^ 1, k1 = (kk + 1) << 6;
    bool pf = (kk + 1 < ntk);
    { // P1
      Bf0[0] = ldsB(d, 0, 0); Bf0[1] = ldsB(d, 0, 1);
#pragma unroll
      for (int mi = 0; mi < 4; ++mi) { Af[mi][0] = ldsA(d, mi, 0); Af[mi][1] = ldsA(d, mi, 1); }
      if (pf) { stA(e, k1); stB(e, 0, k1); stB(e, 1, k1); }
      PH_OPEN();
#pragma unroll
      for (int mi = 0; mi < 4; ++mi) {
        acc[mi][0] = __builtin_amdgcn_mfma_f32_16x16x32_bf16(Af[mi][0], Bf0[0], acc[mi][0], 0, 0, 0);
        acc[mi][0] = __builtin_amdgcn_mfma_f32_16x16x32_bf16(Af[mi][1], Bf0[1], acc[mi][0], 0, 0, 0);
      }
      __builtin_amdgcn_s_setprio(0);
      if (pf) { asm volatile("s_waitcnt vmcnt(3)" ::: "memory"); }
      else    { asm volatile("s_waitcnt vmcnt(0)" ::: "memory"); }
      __builtin_amdgcn_s_barrier();
    }
    { // P2
      Bf1[0] = ldsB(d, 1, 0); Bf1[1] = ldsB(d, 1, 1);
      if (pf) { stB(e, 2, k1); stB(e, 3, k1); }
      PH_OPEN();
#pragma unroll
      for (int mi = 0; mi < 4; ++mi) {
        acc[mi][1] = __builtin_amdgcn_mfma_f32_16x16x32_bf16(Af[mi][0], Bf1[0], acc[mi][1], 0, 0, 0);
        acc[mi][1] = __builtin_amdgcn_mfma_f32_16x16x32_bf16(Af[mi][1], Bf1[1], acc[mi][1], 0, 0, 0);
      }
      __builtin_amdgcn_s_setprio(0);
      if (pf) { asm volatile("s_waitcnt vmcnt(2)" ::: "memory"); }
      __builtin_amdgcn_s_barrier();
    }
  }
#undef PH_OPEN

  float* fb = (float*)sm;
  int fbase = wv * 2048;
  float bv[2];
  bv[0] = bias[n0 + wn * 32 + l15];
  bv[1] = bias[n0 + wn * 32 + 16 + l15];
#pragma unroll
  for (int mi = 0; mi < 4; ++mi)
#pragma unroll
    for (int f = 0; f < 2; ++f)
#pragma unroll
      for (int r = 0; r < 4; ++r)
        fb[fbase + (mi * 16 + lg * 4 + r) * 32 + f * 16 + l15] = acc[mi][f][r] + bv[f];
  asm volatile("s_waitcnt lgkmcnt(0)" ::: "memory");
  __builtin_amdgcn_sched_barrier(0);
#pragma unroll
  for (int i = 0; i < 8; ++i) {
    int row = i * 8 + (ln >> 3);
    int col = (ln & 7) * 4;
    f32x4 v = *(const f32x4*)&fb[fbase + row * 32 + col];
    *(f32x4*)(&C[(size_t)(m0 + row) * ldc + n0 + wn * 32 + col]) = v;
  }
}

// ---------------------------------------------------------------- FFN1: 128x256 2-phase counted GEMM
__global__ __launch_bounds__(512, 1) void gemmF1_kernel(
    const unsigned short* __restrict__ A, int lda,
    const unsigned short* __restrict__ B, int ldb,
    const float* __restrict__ bias, unsigned short* __restrict__ Cb, int ldc, int K) {
  extern __shared__ unsigned short sm[];      // 131072 B
  int b = blockIdx.x;
  int c = (int)gridDim.x >> 3;
  int wg = (b & 7) * c + (b >> 3);            // XCD-contiguous (grid % 8 == 0)
  int mt = wg & 15, nt = wg >> 4;
  int m0 = mt * 128, n0 = nt * 256;

  int tid = threadIdx.x, ln = tid & 63, wv = tid >> 6;
  int l15 = ln & 15, lg = ln >> 4;
  int wm = wv >> 2, wn = wv & 3;              // wave tile 64x64
  int l7 = l15 & 7;

  int srow = tid >> 3, sblk = (tid & 7) ^ (srow & 7);
  const unsigned short* Ab = A + (size_t)(m0 + srow) * lda + sblk * 8;
  const unsigned short* BbG[4];
#pragma unroll
  for (int g = 0; g < 4; ++g) {
    int p = g * 64 + srow;
    int j = p & 127;
    int r = ((j >> 5) << 6) + ((p >> 7) << 5) + (j & 31);   // inverse row permutation
    BbG[g] = B + (size_t)(n0 + r) * ldb + sblk * 8;
  }
  auto stA = [&](int e, int g, int k0) {      // g in {0,1}
    gload16(Ab + ((size_t)g * 64) * lda + k0, &sm[e * 8192 + g * 4096 + wv * 512]);
  };
  auto stB = [&](int e, int g, int k0) {      // g in {0..3}
    gload16(BbG[g] + k0, &sm[16384 + e * 16384 + g * 4096 + wv * 512]);
  };

  auto ldsA = [&](int d, int mi, int ks) -> bf16x8 {
    int row = wm * 64 + mi * 16 + l15;
    return asbf(*(const u16x8*)&sm[d * 8192 + row * 64 + (((ks << 2) | lg) ^ l7) * 8]);
  };
  auto ldsB = [&](int d, int ni, int ks) -> bf16x8 {
    int p = ((ni >> 1) << 7) + wn * 32 + ((ni & 1) << 4) + l15;   // permuted row
    return asbf(*(const u16x8*)&sm[16384 + d * 16384 + p * 64 + (((ks << 2) | lg) ^ l7) * 8]);
  };

  f32x4 acc[4][4] = {};
  bf16x8 Af[4][2], Bf01[2][2], Bf23[2][2];

#define PH_OPEN() __builtin_amdgcn_s_barrier(); \
  asm volatile("s_waitcnt lgkmcnt(0)" ::: "memory"); \
  __builtin_amdgcn_sched_barrier(0); __builtin_amdgcn_s_setprio(1)

  stA(0, 0, 0); stA(0, 1, 0); stB(0, 0, 0); stB(0, 1, 0);
  stB(0, 2, 0); stB(0, 3, 0);
  asm volatile("s_waitcnt vmcnt(2)" ::: "memory");
  __builtin_amdgcn_s_barrier();

  int ntk = K >> 6;
  for (int kk = 0; kk < ntk; ++kk) {
    int d = kk & 1, e = d ^ 1, k1 = (kk + 1) << 6;
    bool pf = (kk + 1 < ntk);
    { // P1
#pragma unroll
      for (int ni = 0; ni < 2; ++ni) { Bf01[ni][0] = ldsB(d, ni, 0); Bf01[ni][1] = ldsB(d, ni, 1); }
#pragma unroll
      for (int mi = 0; mi < 4; ++mi) { Af[mi][0] = ldsA(d, mi, 0); Af[mi][1] = ldsA(d, mi, 1); }
      if (pf) { stA(e, 0, k1); stA(e, 1, k1); stB(e, 0, k1); stB(e, 1, k1); }
      PH_OPEN();
#pragma unroll
      for (int mi = 0; mi < 4; ++mi)
#pragma unroll
        for (int ni = 0; ni < 2; ++ni) {
          acc[mi][ni] = __builtin_amdgcn_mfma_f32_16x16x32_bf16(Af[mi][0], Bf01[ni][0], acc[mi][ni], 0, 0, 0);
          acc[mi][ni] = __builtin_amdgcn_mfma_f32_16x16x32_bf16(Af[mi][1], Bf01[ni][1], acc[mi][ni], 0, 0, 0);
        }
      __builtin_amdgcn_s_setprio(0);
      if (pf) { asm volatile("s_waitcnt vmcnt(4)" ::: "memory"); }
      else    { asm volatile("s_waitcnt vmcnt(0)" ::: "memory"); }
      __builtin_amdgcn_s_barrier();
    }
    { // P2
#pragma unroll
      for (int ni = 0; ni < 2; ++ni) { Bf23[ni][0] = ldsB(d, 2 + ni, 0); Bf23[ni][1] = ldsB(d, 2 + ni, 1); }
      if (pf) { stB(e, 2, k1); stB(e, 3, k1); }
      PH_OPEN();
#pragma unroll
      for (int mi = 0; mi < 4; ++mi)
#pragma unroll
        for (int ni = 0; ni < 2; ++ni) {
          acc[mi][2 + ni] = __builtin_amdgcn_mfma_f32_16x16x32_bf16(Af[mi][0], Bf23[ni][0], acc[mi][2 + ni], 0, 0, 0);
          acc[mi][2 + ni] = __builtin_amdgcn_mfma_f32_16x16x32_bf16(Af[mi][1], Bf23[ni][1], acc[mi][2 + ni], 0, 0, 0);
        }
      __builtin_amdgcn_s_setprio(0);
      if (pf) { asm volatile("s_waitcnt vmcnt(2)" ::: "memory"); }
      __builtin_amdgcn_s_barrier();
    }
  }
#undef PH_OPEN

  float* fb = (float*)sm;
  int fbase = wv * 4096;
  float bv[4];
#pragma unroll
  for (int ni = 0; ni < 4; ++ni) bv[ni] = bias[n0 + wn * 64 + ni * 16 + l15];
#pragma unroll
  for (int mi = 0; mi < 4; ++mi)
#pragma unroll
    for (int ni = 0; ni < 4; ++ni)
#pragma unroll
      for (int r = 0; r < 4; ++r) {
        float vv = acc[mi][ni][r] + bv[ni];
        vv = 0.5f * vv * (1.f + erff(vv * 0.70710678118f));
        fb[fbase + (mi * 16 + lg * 4 + r) * 64 + ni * 16 + l15] = vv;
      }
  asm volatile("s_waitcnt lgkmcnt(0)" ::: "memory");
  __builtin_amdgcn_sched_barrier(0);
#pragma unroll
  for (int i = 0; i < 8; ++i) {
    int row = i * 8 + (ln >> 3);
    int cc = (ln & 7) * 8;
    f32x4 v0 = *(const f32x4*)&fb[fbase + row * 64 + cc];
    f32x4 v1 = *(const f32x4*)&fb[fbase + row * 64 + cc + 4];
    u16x8 o;
#pragma unroll
    for (int j = 0; j < 4; ++j) { o[j] = f2bf(v0[j]); o[j + 4] = f2bf(v1[j]); }
    *(u16x8*)(Cb + (size_t)(m0 + wm * 64 + row) * ldc + n0 + wn * 64 + cc) = o;
  }
}

// ----------------------------------------------------------------
extern "C" void kernel_launch(void* const* d_in, const int* in_sizes, int n_in,
                              void* d_out, int out_size, void* d_ws, size_t ws_size,
                              hipStream_t stream) {
  const int* x = (const int*)d_in[0];
  const float* tok = (const float*)d_in[1];
  const float* pos = (const float*)d_in[2];
  const float* wq = (const float*)d_in[3];
  const float* wk = (const float*)d_in[4];
  const float* wv = (const float*)d_in[5];
  const float* wo = (const float*)d_in[6];
  const float* bo = (const float*)d_in[7];
  const float* ln1g = (const float*)d_in[8];
  const float* ln1b = (const float*)d_in[9];
  const float* ln2g = (const float*)d_in[10];
  const float* ln2b = (const float*)d_in[11];
  const float* w1 = (const float*)d_in[12];
  const float* b1 = (const float*)d_in[13];
  const float* w2 = (const float*)d_in[14];
  const float* b2 = (const float*)d_in[15];
  const float* outw = (const float*)d_in[16];
  const float* outb = (const float*)d_in[17];
  float* out = (float*)d_out;

  const size_t MiB = 1 << 20;
  const size_t need = 4 * MiB + 65536000;
  if (ws_size < need) return;
  char* base = (char*)d_ws;
  unsigned short* hbf = (unsigned short*)base;            // 4 MiB, persistent
  char* R = base + 4 * MiB;
  float* hf  = (float*)(R);                               // 8 MiB
  float* x1f = (float*)(R + 8 * MiB);                     // 8 MiB
  unsigned short* x1bf = (unsigned short*)(R + 16 * MiB); // 4 MiB
  float* cfA = (float*)(R + 20 * MiB);                    // 8 MiB
  float* cfB = (float*)(R + 28 * MiB);                    // 8 MiB
  unsigned short* qs = (unsigned short*)(R + 36 * MiB);   // 6 slots x 4 MiB
  const size_t SL = 2048ull * 1024;
  unsigned short* qbf = qs;
  unsigned short* kbf = qs + SL;
  unsigned short* vbf = qs + 2 * SL;                      // attn-out
  unsigned short* vtbf = qs + 3 * SL;                     // vt, also wobf
  unsigned short* wobf = vtbf;
  unsigned short* w1bf = qbf;                             // slots 0-1 (8 MiB), q/k dead after attn
  unsigned short* w2bf = qbf;                             // same slots; cvt AFTER gemmF1 consumed w1
  unsigned short* ffbf = vbf;                             // slots 2-5 (16 MiB)
  unsigned short* wqbf = (unsigned short*)(R + 60 * MiB); // 3 x 16384 u16 (96 KB, layers only)
  unsigned short* wkbf = wqbf + 16384;
  unsigned short* wvbf = wkbf + 16384;
  unsigned short* outwbf = (unsigned short*)R;            // 62.5 MiB, after layers

  embed_kernel<<<2048, 256, 0, stream>>>(x, tok, pos, hf, hbf);
  cvt3q_kernel<<<24, 256, 0, stream>>>(wq, wqbf, wk, wkbf, wv, wvbf);
  for (int l = 0; l < 4; ++l) {
    qkvt_kernel<<<dim3(32, 16), 256, 0, stream>>>(hbf, wqbf + l * 4096, wkbf + l * 4096,
                                                  wvbf + l * 4096, qbf, kbf, vtbf);
    attn_kernel<<<dim3(16, 32), 256, 0, stream>>>(qbf, kbf, vtbf, vbf);
    cvt2_kernel<<<2048, 256, 0, stream>>>(wo + (size_t)l * 1048576, wobf, 131072,
                                          w1 + (size_t)l * 4194304, w1bf, 524288);
    gemmF2_kernel<<<256, 512, 81920, stream>>>(
        vbf, 1024, wobf, 1024, bo + l * 1024, cfA, cfB, 512);
    ln_kernel<<<2048, 256, 0, stream>>>(cfA, cfB, hf, ln1g + l * 1024, ln1b + l * 1024,
                                        x1f, x1bf);
    gemmF1_kernel<<<256, 512, 131072, stream>>>(
        x1bf, 1024, w1bf, 1024, b1 + l * 4096, ffbf, 4096, 1024);
    cvt_kernel<<<2048, 256, 0, stream>>>(w2 + (size_t)l * 4194304, w2bf, 524288);
    gemmF2_kernel<<<256, 512, 81920, stream>>>(
        ffbf, 4096, w2bf, 4096, b2 + l * 1024, cfA, cfB, 2048);
    ln_kernel<<<2048, 256, 0, stream>>>(cfA, cfB, x1f, ln2g + l * 1024, ln2b + l * 1024,
                                        hf, hbf);
  }
  cvt_kernel<<<2048, 256, 0, stream>>>(outw, outwbf, 4096000);
  gemmL_kernel<<<4000, 512, 81920, stream>>>(hbf, 1024, outwbf, 1024, outb, out, 32000, 1024);
}

// Round 16
// 763.210 us; speedup vs baseline: 1.0674x; 1.0674x over previous
//
#include <hip/hip_runtime.h>
#include <math.h>

typedef float f32x4 __attribute__((ext_vector_type(4)));
typedef unsigned short u16x8 __attribute__((ext_vector_type(8)));
typedef unsigned short u16x4 __attribute__((ext_vector_type(4)));
typedef __bf16 bf16x8 __attribute__((ext_vector_type(8)));
typedef unsigned int u32;

#define DEV static __device__ __forceinline__

DEV unsigned short f2bf(float f) {            // native cast -> v_cvt_pk_bf16_f32 (m240)
  __bf16 h = (__bf16)f;
  return __builtin_bit_cast(unsigned short, h);
}
DEV float bf2f(unsigned short s) { return __uint_as_float(((unsigned)s) << 16); }
DEV bf16x8 asbf(u16x8 v) { return __builtin_bit_cast(bf16x8, v); }

DEV void gload16(const void* g, void* l) {    // async global->LDS, 16B/lane, wave-uniform LDS base
  __builtin_amdgcn_global_load_lds((const __attribute__((address_space(1))) u32*)g,
                                   (__attribute__((address_space(3))) u32*)l, 16, 0, 0);
}

// ---------------------------------------------------------------- f32 -> bf16 bulk convert
__global__ void cvt_kernel(const float* __restrict__ in, unsigned short* __restrict__ out, int n8) {
  for (int i = blockIdx.x * 256 + threadIdx.x; i < n8; i += gridDim.x * 256) {
    const float* s = in + (size_t)i * 8;
    f32x4 a = *(const f32x4*)s, b = *(const f32x4*)(s + 4);
    u16x8 o;
    for (int j = 0; j < 4; ++j) { o[j] = f2bf(a[j]); o[j + 4] = f2bf(b[j]); }
    *(u16x8*)(out + (size_t)i * 8) = o;
  }
}

// two-segment convert (wo + w1 in one dispatch)
__global__ void cvt2_kernel(const float* __restrict__ s0, unsigned short* __restrict__ d0, int na,
                            const float* __restrict__ s1, unsigned short* __restrict__ d1, int nb) {
  int total = na + nb;
  for (int i = blockIdx.x * 256 + threadIdx.x; i < total; i += gridDim.x * 256) {
    const float* s; unsigned short* d; int k;
    if (i < na) { s = s0; d = d0; k = i; } else { s = s1; d = d1; k = i - na; }
    f32x4 a = *(const f32x4*)(s + (size_t)k * 8), b = *(const f32x4*)(s + (size_t)k * 8 + 4);
    u16x8 o;
    for (int j = 0; j < 4; ++j) { o[j] = f2bf(a[j]); o[j + 4] = f2bf(b[j]); }
    *(u16x8*)(d + (size_t)k * 8) = o;
  }
}

// three-segment convert (all qkv weights, one dispatch; each segment n8=2048)
__global__ void cvt3q_kernel(const float* __restrict__ s0, unsigned short* __restrict__ d0,
                             const float* __restrict__ s1, unsigned short* __restrict__ d1,
                             const float* __restrict__ s2, unsigned short* __restrict__ d2) {
  int i = blockIdx.x * 256 + threadIdx.x;
  if (i >= 6144) return;
  const float* s; unsigned short* d; int k = i & 2047;
  int seg = i >> 11;
  s = (seg == 0) ? s0 : (seg == 1) ? s1 : s2;
  d = (seg == 0) ? d0 : (seg == 1) ? d1 : d2;
  f32x4 a = *(const f32x4*)(s + (size_t)k * 8), b = *(const f32x4*)(s + (size_t)k * 8 + 4);
  u16x8 o;
  for (int j = 0; j < 4; ++j) { o[j] = f2bf(a[j]); o[j + 4] = f2bf(b[j]); }
  *(u16x8*)(d + (size_t)k * 8) = o;
}

// ---------------------------------------------------------------- embed
__global__ void embed_kernel(const int* __restrict__ x, const float* __restrict__ tok,
                             const float* __restrict__ pos, float* __restrict__ h,
                             unsigned short* __restrict__ hbf) {
  int t = blockIdx.x, tid = threadIdx.x;
  int v = x[t], s = t & 1023;                 // S = 1024
  f32x4 a = *(const f32x4*)(tok + (size_t)v * 1024 + tid * 4);
  f32x4 b = *(const f32x4*)(pos + (size_t)s * 1024 + tid * 4);
  f32x4 r = a + b;
  *(f32x4*)(h + (size_t)t * 1024 + tid * 4) = r;
  u16x4 rb;
  for (int i = 0; i < 4; ++i) rb[i] = f2bf(r[i]);
  *(u16x4*)(hbf + (size_t)t * 1024 + tid * 4) = rb;
}

// ---------------------------------------------------------------- LayerNorm(preA + preB + res)
__global__ __launch_bounds__(256) void ln_kernel(const float* __restrict__ preA,
    const float* __restrict__ preB, const float* __restrict__ res,
    const float* __restrict__ g, const float* __restrict__ bta,
    float* __restrict__ outf, unsigned short* __restrict__ outbf) {
  int row = blockIdx.x, tid = threadIdx.x;
  size_t base = (size_t)row * 1024 + tid * 4;
  f32x4 xv = *(const f32x4*)(preA + base);
  xv += *(const f32x4*)(preB + base);
  xv += *(const f32x4*)(res + base);
  float s = xv[0] + xv[1] + xv[2] + xv[3];
  float s2 = xv[0]*xv[0] + xv[1]*xv[1] + xv[2]*xv[2] + xv[3]*xv[3];
  for (int m = 1; m < 64; m <<= 1) { s += __shfl_xor(s, m); s2 += __shfl_xor(s2, m); }
  __shared__ float red[8];
  int w = tid >> 6;
  if ((tid & 63) == 0) { red[w * 2] = s; red[w * 2 + 1] = s2; }
  __syncthreads();
  s = red[0] + red[2] + red[4] + red[6];
  s2 = red[1] + red[3] + red[5] + red[7];
  float mu = s * (1.f / 1024.f);
  float var = s2 * (1.f / 1024.f) - mu * mu;
  float rs = rsqrtf(var + 1e-5f);
  f32x4 gv = *(const f32x4*)(g + tid * 4);
  f32x4 bv = *(const f32x4*)(bta + tid * 4);
  f32x4 o; u16x4 ob;
  for (int i = 0; i < 4; ++i) { o[i] = (xv[i] - mu) * rs * gv[i] + bv[i]; ob[i] = f2bf(o[i]); }
  *(f32x4*)(outf + base) = o;
  *(u16x4*)(outbf + base) = ob;
}

// ---------------------------------------------------------------- QKV via MFMA + fused V-transpose
__global__ __launch_bounds__(256) void qkvt_kernel(const unsigned short* __restrict__ hbf,
    const unsigned short* __restrict__ wqb, const unsigned short* __restrict__ wkb,
    const unsigned short* __restrict__ wvb,
    unsigned short* __restrict__ q, unsigned short* __restrict__ k,
    unsigned short* __restrict__ vt) {
  __shared__ unsigned short T[64 * 72];
  int tid = threadIdx.x, ln = tid & 63, w = tid >> 6;
  int l15 = ln & 15, lg = ln >> 4;
  int st = blockIdx.x, hh = blockIdx.y;
  int t0 = st * 64 + w * 16;                  // token base (t = b*1024+s flattened)
  const unsigned short* xp = hbf + (size_t)(t0 + l15) * 1024 + hh * 64 + lg * 8;
  bf16x8 xa0 = asbf(*(const u16x8*)xp);
  bf16x8 xa1 = asbf(*(const u16x8*)(xp + 32));
  const unsigned short* wp[3] = {wqb, wkb, wvb};
  f32x4 acc[3][4] = {};
#pragma unroll
  for (int m = 0; m < 3; ++m) {
    __builtin_amdgcn_s_setprio(1);
#pragma unroll
    for (int ni = 0; ni < 4; ++ni) {
      const unsigned short* wb = wp[m] + (size_t)(ni * 16 + l15) * 64 + lg * 8;
      bf16x8 w0 = asbf(*(const u16x8*)wb);
      bf16x8 w1 = asbf(*(const u16x8*)(wb + 32));
      acc[m][ni] = __builtin_amdgcn_mfma_f32_16x16x32_bf16(xa0, w0, acc[m][ni], 0, 0, 0);
      acc[m][ni] = __builtin_amdgcn_mfma_f32_16x16x32_bf16(xa1, w1, acc[m][ni], 0, 0, 0);
    }
    __builtin_amdgcn_s_setprio(0);
  }
  unsigned short* outp[2] = {q, k};
#pragma unroll
  for (int m = 0; m < 2; ++m)
#pragma unroll
    for (int ni = 0; ni < 4; ++ni)
#pragma unroll
      for (int r = 0; r < 4; ++r)
        outp[m][(size_t)(t0 + 4 * lg + r) * 1024 + hh * 64 + ni * 16 + l15] = f2bf(acc[m][ni][r]);
#pragma unroll
  for (int ni = 0; ni < 4; ++ni)
#pragma unroll
    for (int r = 0; r < 4; ++r)
      T[(ni * 16 + l15) * 72 + (w * 16 + 4 * lg + r)] = f2bf(acc[2][ni][r]);
  __syncthreads();
  int b = st >> 4, sb = (st & 15) * 64;
#pragma unroll
  for (int j = 0; j < 2; ++j) {
    int idx = tid + 256 * j; int e = idx >> 3, s8 = (idx & 7) * 8;
    *(u16x8*)(vt + ((size_t)((b * 16 + hh) * 64 + e)) * 1024 + sb + s8) =
        *(const u16x8*)&T[e * 72 + s8];
  }
}

// ---------------------------------------------------------------- flash attention, KVBLK=128, T13+T14+T5
__global__ __launch_bounds__(256, 2) void attn_kernel(const unsigned short* __restrict__ qb,
    const unsigned short* __restrict__ kb, const unsigned short* __restrict__ vtb,
    unsigned short* __restrict__ ob) {
  constexpr int PK = 72, PV = 136, PP = 136;
  __shared__ unsigned short Ks[128 * PK], Vs[64 * PV], Ps[4][16 * PP];
  int tid = threadIdx.x, lane = tid & 63, w = tid >> 6;
  int l15 = lane & 15, lg = lane >> 4;
  int qt = blockIdx.x, bh = blockIdx.y, b = bh >> 4, hh = bh & 15;
  int q0 = qt * 64 + w * 16;
  const unsigned short* qrow = qb + ((size_t)(b * 1024 + q0 + l15) * 16 + hh) * 64 + lg * 8;
  bf16x8 qa0 = asbf(*(const u16x8*)qrow);
  bf16x8 qa1 = asbf(*(const u16x8*)(qrow + 32));
  {                                            // pre-scale Q by 1/32 (exact power-of-2)
    const __bf16 s = (__bf16)0.03125f;
#pragma unroll
    for (int i = 0; i < 8; ++i) { qa0[i] = qa0[i] * s; qa1[i] = qa1[i] * s; }
  }
  float m_[4] = {-1e30f, -1e30f, -1e30f, -1e30f};
  float ls[4] = {0.f, 0.f, 0.f, 0.f};
  f32x4 oacc[4] = {};

  u16x8 KR[4], VR[4];                         // T14: reg-staged next tile
  auto loadT = [&](int kt) {
#pragma unroll
    for (int j = 0; j < 4; ++j) {
      int idx = tid + 256 * j;
      int r = idx >> 3, c0 = (idx & 7) * 8;
      KR[j] = *(const u16x8*)(kb + ((size_t)(b * 1024 + kt * 128 + r) * 16 + hh) * 64 + c0);
      int rv = idx >> 4, cv = (idx & 15) * 8;
      VR[j] = *(const u16x8*)(vtb + ((size_t)((b * 16 + hh) * 64) + rv) * 1024 + kt * 128 + cv);
    }
  };
  auto writeT = [&]() {
#pragma unroll
    for (int j = 0; j < 4; ++j) {
      int idx = tid + 256 * j;
      int r = idx >> 3, c0 = (idx & 7) * 8;
      *(u16x8*)(&Ks[r * PK + c0]) = KR[j];
      int rv = idx >> 4, cv = (idx & 15) * 8;
      *(u16x8*)(&Vs[rv * PV + cv]) = VR[j];
    }
  };
  loadT(0); writeT();
  __syncthreads();

  for (int kt = 0; kt < 8; ++kt) {
    f32x4 sf[8] = {};
    __builtin_amdgcn_s_setprio(1);
#pragma unroll
    for (int n = 0; n < 8; ++n) {
      bf16x8 k0 = asbf(*(const u16x8*)(&Ks[(n * 16 + l15) * PK + lg * 8]));
      bf16x8 k1 = asbf(*(const u16x8*)(&Ks[(n * 16 + l15) * PK + 32 + lg * 8]));
      sf[n] = __builtin_amdgcn_mfma_f32_16x16x32_bf16(qa0, k0, sf[n], 0, 0, 0);
      sf[n] = __builtin_amdgcn_mfma_f32_16x16x32_bf16(qa1, k1, sf[n], 0, 0, 0);
    }
    __builtin_amdgcn_s_setprio(0);
    if (kt < 7) loadT(kt + 1);                // issue-early: latency hides under softmax+PV
    float tm[4];
#pragma unroll
    for (int r = 0; r < 4; ++r) {
      float t0 = fmaxf(fmaxf(fmaxf(sf[0][r], sf[1][r]), fmaxf(sf[2][r], sf[3][r])),
                       fmaxf(fmaxf(sf[4][r], sf[5][r]), fmaxf(sf[6][r], sf[7][r])));
      for (int msk = 1; msk < 16; msk <<= 1) t0 = fmaxf(t0, __shfl_xor(t0, msk));
      tm[r] = t0;
    }
    bool need = false;
#pragma unroll
    for (int r = 0; r < 4; ++r) need |= (tm[r] > m_[r] + 8.f);
    if (__any(need)) {
#pragma unroll
      for (int r = 0; r < 4; ++r) {
        float nm = fmaxf(m_[r], tm[r]);
        float sc = __expf(m_[r] - nm);
        ls[r] *= sc;
#pragma unroll
        for (int n = 0; n < 4; ++n) oacc[n][r] *= sc;
        m_[r] = nm;
      }
    }
    float rsum[4] = {0.f, 0.f, 0.f, 0.f};
    unsigned short pb[8][4];
#pragma unroll
    for (int n = 0; n < 8; ++n)
#pragma unroll
      for (int r = 0; r < 4; ++r) {
        float pv = __expf(sf[n][r] - m_[r]);
        rsum[r] += pv;
        pb[n][r] = f2bf(pv);
      }
#pragma unroll
    for (int r = 0; r < 4; ++r) {
      float t0 = rsum[r];
      for (int msk = 1; msk < 16; msk <<= 1) t0 += __shfl_xor(t0, msk);
      ls[r] += t0;
    }
    unsigned short* pw = Ps[w];                // per-wave region: no block barrier needed
#pragma unroll
    for (int n = 0; n < 8; ++n)
#pragma unroll
      for (int r = 0; r < 4; ++r)
        pw[(4 * lg + r) * PP + n * 16 + l15] = pb[n][r];
    asm volatile("s_waitcnt lgkmcnt(0)" ::: "memory");
    __builtin_amdgcn_sched_barrier(0);
    bf16x8 pa[4];
#pragma unroll
    for (int ks = 0; ks < 4; ++ks)
      pa[ks] = asbf(*(const u16x8*)(&pw[l15 * PP + ks * 32 + lg * 8]));
    __builtin_amdgcn_s_setprio(1);
#pragma unroll
    for (int n = 0; n < 4; ++n) {
#pragma unroll
      for (int ks = 0; ks < 4; ++ks) {
        bf16x8 v0 = asbf(*(const u16x8*)(&Vs[(n * 16 + l15) * PV + ks * 32 + lg * 8]));
        oacc[n] = __builtin_amdgcn_mfma_f32_16x16x32_bf16(pa[ks], v0, oacc[n], 0, 0, 0);
      }
    }
    __builtin_amdgcn_s_setprio(0);
    __syncthreads();
    if (kt < 7) { writeT(); __syncthreads(); }
  }
#pragma unroll
  for (int n = 0; n < 4; ++n)
#pragma unroll
    for (int r = 0; r < 4; ++r) {
      float o = oacc[n][r] / ls[r];
      ob[((size_t)(b * 1024 + q0 + 4 * lg + r) * 16 + hh) * 64 + n * 16 + l15] = f2bf(o);
    }
}

// ---------------------------------------------------------------- wo/FFN2: 64x256 2-phase counted GEMM, split-K=2
// Cf[kh] = A @ B^T (+bias if kh==0), f32 out [2048,1024]. grid = 256 (32 mt x 4 nt x 2 kh), 512 thr.
// LDS 81920 B: A[2][64][64] @0, B[2][256][64] @8192. B rows permuted p = f*128+wn*16+l15.
// Ledger (5 gloads/tile: P1{A,Bg0,Bg1}, P2{Bg2,Bg3}): close P1 vmcnt(3), close P2 vmcnt(2).
__global__ __launch_bounds__(512, 2) void gemmF2_kernel(
    const unsigned short* __restrict__ A, int lda,
    const unsigned short* __restrict__ B, int ldb,
    const float* __restrict__ bias,
    float* __restrict__ CfA, float* __restrict__ CfB, int Ksub) {
  extern __shared__ unsigned short sm[];
  int b = blockIdx.x;
  int c = (int)gridDim.x >> 3;
  int wg = (b & 7) * c + (b >> 3);            // XCD-contiguous (grid % 8 == 0)
  int mt = wg & 31, nt = (wg >> 5) & 3, kh = wg >> 7;
  int m0 = mt * 64, n0 = nt * 256;
  const unsigned short* Ae = A + (size_t)kh * Ksub;
  const unsigned short* Be = B + (size_t)kh * Ksub;

  int tid = threadIdx.x, ln = tid & 63, wv = tid >> 6;
  int l15 = ln & 15, lg = ln >> 4;
  int wn = wv;                                // 8 N-waves, cols wn*32
  int l7 = l15 & 7;

  int srow = tid >> 3, sblk = (tid & 7) ^ (srow & 7);
  const unsigned short* Ab = Ae + (size_t)(m0 + srow) * lda + sblk * 8;
  const unsigned short* BbG[4];
#pragma unroll
  for (int g = 0; g < 4; ++g) {
    int p = g * 64 + srow;
    int f = p >> 7, wnn = (p >> 4) & 7;
    int r = wnn * 32 + f * 16 + (p & 15);     // inverse row permutation
    BbG[g] = Be + (size_t)(n0 + r) * ldb + sblk * 8;
  }
  auto stA = [&](int e, int k0) {
    gload16(Ab + k0, &sm[e * 4096 + wv * 512]);
  };
  auto stB = [&](int e, int g, int k0) {
    gload16(BbG[g] + k0, &sm[8192 + e * 16384 + g * 4096 + wv * 512]);
  };
  auto ldsA = [&](int d, int mi, int ks) -> bf16x8 {
    int row = mi * 16 + l15;
    return asbf(*(const u16x8*)&sm[d * 4096 + row * 64 + (((ks << 2) | lg) ^ l7) * 8]);
  };
  auto ldsB = [&](int d, int f, int ks) -> bf16x8 {
    int p = f * 128 + wn * 16 + l15;          // permuted row
    return asbf(*(const u16x8*)&sm[8192 + d * 16384 + p * 64 + (((ks << 2) | lg) ^ l7) * 8]);
  };

  f32x4 acc[4][2] = {};
  bf16x8 Af[4][2], Bf0[2], Bf1[2];

#define PH_OPEN() __builtin_amdgcn_s_barrier(); \
  asm volatile("s_waitcnt lgkmcnt(0)" ::: "memory"); \
  __builtin_amdgcn_sched_barrier(0); __builtin_amdgcn_s_setprio(1)

  stA(0, 0); stB(0, 0, 0); stB(0, 1, 0); stB(0, 2, 0); stB(0, 3, 0);
  asm volatile("s_waitcnt vmcnt(2)" ::: "memory");
  __builtin_amdgcn_s_barrier();

  int ntk = Ksub >> 6;
  for (int kk = 0; kk < ntk; ++kk) {
    int d = kk & 1, e = d ^ 1, k1 = (kk + 1) << 6;
    bool pf = (kk + 1 < ntk);
    { // P1
      Bf0[0] = ldsB(d, 0, 0); Bf0[1] = ldsB(d, 0, 1);
#pragma unroll
      for (int mi = 0; mi < 4; ++mi) { Af[mi][0] = ldsA(d, mi, 0); Af[mi][1] = ldsA(d, mi, 1); }
      if (pf) { stA(e, k1); stB(e, 0, k1); stB(e, 1, k1); }
      PH_OPEN();
#pragma unroll
      for (int mi = 0; mi < 4; ++mi) {
        acc[mi][0] = __builtin_amdgcn_mfma_f32_16x16x32_bf16(Af[mi][0], Bf0[0], acc[mi][0], 0, 0, 0);
        acc[mi][0] = __builtin_amdgcn_mfma_f32_16x16x32_bf16(Af[mi][1], Bf0[1], acc[mi][0], 0, 0, 0);
      }
      __builtin_amdgcn_s_setprio(0);
      if (pf) { asm volatile("s_waitcnt vmcnt(3)" ::: "memory"); }
      else    { asm volatile("s_waitcnt vmcnt(0)" ::: "memory"); }
      __builtin_amdgcn_s_barrier();
    }
    { // P2
      Bf1[0] = ldsB(d, 1, 0); Bf1[1] = ldsB(d, 1, 1);
      if (pf) { stB(e, 2, k1); stB(e, 3, k1); }
      PH_OPEN();
#pragma unroll
      for (int mi = 0; mi < 4; ++mi) {
        acc[mi][1] = __builtin_amdgcn_mfma_f32_16x16x32_bf16(Af[mi][0], Bf1[0], acc[mi][1], 0, 0, 0);
        acc[mi][1] = __builtin_amdgcn_mfma_f32_16x16x32_bf16(Af[mi][1], Bf1[1], acc[mi][1], 0, 0, 0);
      }
      __builtin_amdgcn_s_setprio(0);
      if (pf) { asm volatile("s_waitcnt vmcnt(2)" ::: "memory"); }
      __builtin_amdgcn_s_barrier();
    }
  }
#undef PH_OPEN

  float* fb = (float*)sm;
  int fbase = wv * 2048;
  float* Cf = (kh == 0) ? CfA : CfB;
  float bv[2] = {0.f, 0.f};
  if (kh == 0) { bv[0] = bias[n0 + wn * 32 + l15]; bv[1] = bias[n0 + wn * 32 + 16 + l15]; }
#pragma unroll
  for (int mi = 0; mi < 4; ++mi)
#pragma unroll
    for (int f = 0; f < 2; ++f)
#pragma unroll
      for (int r = 0; r < 4; ++r)
        fb[fbase + (mi * 16 + lg * 4 + r) * 32 + f * 16 + l15] = acc[mi][f][r] + bv[f];
  asm volatile("s_waitcnt lgkmcnt(0)" ::: "memory");
  __builtin_amdgcn_sched_barrier(0);
#pragma unroll
  for (int i = 0; i < 8; ++i) {
    int row = i * 8 + (ln >> 3);
    int col = (ln & 7) * 4;
    f32x4 v = *(const f32x4*)&fb[fbase + row * 32 + col];
    *(f32x4*)(&Cf[(size_t)(m0 + row) * 1024 + n0 + wn * 32 + col]) = v;
  }
}

// ---------------------------------------------------------------- FFN1: 128x256 2-phase counted GEMM
__global__ __launch_bounds__(512, 1) void gemmF1_kernel(
    const unsigned short* __restrict__ A, int lda,
    const unsigned short* __restrict__ B, int ldb,
    const float* __restrict__ bias, unsigned short* __restrict__ Cb, int ldc, int K) {
  extern __shared__ unsigned short sm[];      // 131072 B
  int b = blockIdx.x;
  int c = (int)gridDim.x >> 3;
  int wg = (b & 7) * c + (b >> 3);            // XCD-contiguous (grid % 8 == 0)
  int mt = wg & 15, nt = wg >> 4;
  int m0 = mt * 128, n0 = nt * 256;

  int tid = threadIdx.x, ln = tid & 63, wv = tid >> 6;
  int l15 = ln & 15, lg = ln >> 4;
  int wm = wv >> 2, wn = wv & 3;              // wave tile 64x64
  int l7 = l15 & 7;

  int srow = tid >> 3, sblk = (tid & 7) ^ (srow & 7);
  const unsigned short* Ab = A + (size_t)(m0 + srow) * lda + sblk * 8;
  const unsigned short* BbG[4];
#pragma unroll
  for (int g = 0; g < 4; ++g) {
    int p = g * 64 + srow;
    int j = p & 127;
    int r = ((j >> 5) << 6) + ((p >> 7) << 5) + (j & 31);   // inverse row permutation
    BbG[g] = B + (size_t)(n0 + r) * ldb + sblk * 8;
  }
  auto stA = [&](int e, int g, int k0) {      // g in {0,1}
    gload16(Ab + ((size_t)g * 64) * lda + k0, &sm[e * 8192 + g * 4096 + wv * 512]);
  };
  auto stB = [&](int e, int g, int k0) {      // g in {0..3}
    gload16(BbG[g] + k0, &sm[16384 + e * 16384 + g * 4096 + wv * 512]);
  };

  auto ldsA = [&](int d, int mi, int ks) -> bf16x8 {
    int row = wm * 64 + mi * 16 + l15;
    return asbf(*(const u16x8*)&sm[d * 8192 + row * 64 + (((ks << 2) | lg) ^ l7) * 8]);
  };
  auto ldsB = [&](int d, int ni, int ks) -> bf16x8 {
    int p = ((ni >> 1) << 7) + wn * 32 + ((ni & 1) << 4) + l15;   // permuted row
    return asbf(*(const u16x8*)&sm[16384 + d * 16384 + p * 64 + (((ks << 2) | lg) ^ l7) * 8]);
  };

  f32x4 acc[4][4] = {};
  bf16x8 Af[4][2], Bf01[2][2], Bf23[2][2];

#define PH_OPEN() __builtin_amdgcn_s_barrier(); \
  asm volatile("s_waitcnt lgkmcnt(0)" ::: "memory"); \
  __builtin_amdgcn_sched_barrier(0); __builtin_amdgcn_s_setprio(1)

  stA(0, 0, 0); stA(0, 1, 0); stB(0, 0, 0); stB(0, 1, 0);
  stB(0, 2, 0); stB(0, 3, 0);
  asm volatile("s_waitcnt vmcnt(2)" ::: "memory");
  __builtin_amdgcn_s_barrier();

  int ntk = K >> 6;
  for (int kk = 0; kk < ntk; ++kk) {
    int d = kk & 1, e = d ^ 1, k1 = (kk + 1) << 6;
    bool pf = (kk + 1 < ntk);
    { // P1
#pragma unroll
      for (int ni = 0; ni < 2; ++ni) { Bf01[ni][0] = ldsB(d, ni, 0); Bf01[ni][1] = ldsB(d, ni, 1); }
#pragma unroll
      for (int mi = 0; mi < 4; ++mi) { Af[mi][0] = ldsA(d, mi, 0); Af[mi][1] = ldsA(d, mi, 1); }
      if (pf) { stA(e, 0, k1); stA(e, 1, k1); stB(e, 0, k1); stB(e, 1, k1); }
      PH_OPEN();
#pragma unroll
      for (int mi = 0; mi < 4; ++mi)
#pragma unroll
        for (int ni = 0; ni < 2; ++ni) {
          acc[mi][ni] = __builtin_amdgcn_mfma_f32_16x16x32_bf16(Af[mi][0], Bf01[ni][0], acc[mi][ni], 0, 0, 0);
          acc[mi][ni] = __builtin_amdgcn_mfma_f32_16x16x32_bf16(Af[mi][1], Bf01[ni][1], acc[mi][ni], 0, 0, 0);
        }
      __builtin_amdgcn_s_setprio(0);
      if (pf) { asm volatile("s_waitcnt vmcnt(4)" ::: "memory"); }
      else    { asm volatile("s_waitcnt vmcnt(0)" ::: "memory"); }
      __builtin_amdgcn_s_barrier();
    }
    { // P2
#pragma unroll
      for (int ni = 0; ni < 2; ++ni) { Bf23[ni][0] = ldsB(d, 2 + ni, 0); Bf23[ni][1] = ldsB(d, 2 + ni, 1); }
      if (pf) { stB(e, 2, k1); stB(e, 3, k1); }
      PH_OPEN();
#pragma unroll
      for (int mi = 0; mi < 4; ++mi)
#pragma unroll
        for (int ni = 0; ni < 2; ++ni) {
          acc[mi][2 + ni] = __builtin_amdgcn_mfma_f32_16x16x32_bf16(Af[mi][0], Bf23[ni][0], acc[mi][2 + ni], 0, 0, 0);
          acc[mi][2 + ni] = __builtin_amdgcn_mfma_f32_16x16x32_bf16(Af[mi][1], Bf23[ni][1], acc[mi][2 + ni], 0, 0, 0);
        }
      __builtin_amdgcn_s_setprio(0);
      if (pf) { asm volatile("s_waitcnt vmcnt(2)" ::: "memory"); }
      __builtin_amdgcn_s_barrier();
    }
  }
#undef PH_OPEN

  float* fb = (float*)sm;
  int fbase = wv * 4096;
  float bv[4];
#pragma unroll
  for (int ni = 0; ni < 4; ++ni) bv[ni] = bias[n0 + wn * 64 + ni * 16 + l15];
#pragma unroll
  for (int mi = 0; mi < 4; ++mi)
#pragma unroll
    for (int ni = 0; ni < 4; ++ni)
#pragma unroll
      for (int r = 0; r < 4; ++r) {
        float vv = acc[mi][ni][r] + bv[ni];
        vv = 0.5f * vv * (1.f + erff(vv * 0.70710678118f));
        fb[fbase + (mi * 16 + lg * 4 + r) * 64 + ni * 16 + l15] = vv;
      }
  asm volatile("s_waitcnt lgkmcnt(0)" ::: "memory");
  __builtin_amdgcn_sched_barrier(0);
#pragma unroll
  for (int i = 0; i < 8; ++i) {
    int row = i * 8 + (ln >> 3);
    int cc = (ln & 7) * 8;
    f32x4 v0 = *(const f32x4*)&fb[fbase + row * 64 + cc];
    f32x4 v1 = *(const f32x4*)&fb[fbase + row * 64 + cc + 4];
    u16x8 o;
#pragma unroll
    for (int j = 0; j < 4; ++j) { o[j] = f2bf(v0[j]); o[j + 4] = f2bf(v1[j]); }
    *(u16x8*)(Cb + (size_t)(m0 + wm * 64 + row) * ldc + n0 + wn * 64 + cc) = o;
  }
}

// ---------------------------------------------------------------- 256x256 BK=64 4-phase GEMM (logits)
// Best measured logits kernel across 3 tile families (178 us): keep permanently.
__global__ __launch_bounds__(512, 1) void gemm256_kernel(
    const unsigned short* __restrict__ A, int lda,
    const unsigned short* __restrict__ B, int ldb,
    const float* __restrict__ bias, float* __restrict__ C, int ldc, int K) {
  extern __shared__ unsigned short sm[];      // 65536 elems = 128 KiB
  int b = blockIdx.x;
  int c = (int)gridDim.x >> 3;
  int wg = (b & 7) * c + (b >> 3);            // XCD-contiguous (grid % 8 == 0)
  int mt = wg & 7, nt = wg >> 3;
  int m0 = mt * 256, n0 = nt * 256;

  int tid = threadIdx.x, ln = tid & 63, wv = tid >> 6;
  int l15 = ln & 15, lg = ln >> 4;
  int wm = wv >> 2, wn = wv & 3;              // 2M x 4N waves; wave tile 128x64
  int l7 = l15 & 7;

  int srow = tid >> 3, sblk = (tid & 7) ^ (srow & 7);
  const unsigned short* Ab = A + (size_t)(m0 + srow) * lda + sblk * 8;
  const unsigned short* BbG[4];
#pragma unroll
  for (int g = 0; g < 4; ++g) {
    int p = g * 64 + srow;
    int j = p & 127;
    int r = ((j >> 5) << 6) + ((p >> 7) << 5) + (j & 31);
    BbG[g] = B + (size_t)(n0 + r) * ldb + sblk * 8;
  }
  auto stA = [&](int e, int g, int k0) {
    gload16(Ab + ((size_t)g * 64) * lda + k0, &sm[e * 16384 + g * 4096 + wv * 512]);
  };
  auto stB = [&](int e, int g, int k0) {
    gload16(BbG[g] + k0, &sm[32768 + e * 16384 + g * 4096 + wv * 512]);
  };

  auto ldsA = [&](int d, int mi, int ks) -> bf16x8 {
    int row = wm * 128 + mi * 16 + l15;
    return asbf(*(const u16x8*)&sm[d * 16384 + row * 64 + (((ks << 2) | lg) ^ l7) * 8]);
  };
  auto ldsB = [&](int d, int ni, int ks) -> bf16x8 {
    int p = ((ni >> 1) << 7) + wn * 32 + ((ni & 1) << 4) + l15;   // permuted row
    return asbf(*(const u16x8*)&sm[32768 + d * 16384 + p * 64 + (((ks << 2) | lg) ^ l7) * 8]);
  };

  f32x4 acc[8][4] = {};
  bf16x8 Af[4][2], Bf01[2][2], Bf23[2][2];

#define PH_OPEN() __builtin_amdgcn_s_barrier(); \
  asm volatile("s_waitcnt lgkmcnt(0)" ::: "memory"); \
  __builtin_amdgcn_sched_barrier(0); __builtin_amdgcn_s_setprio(1)

  stA(0, 0, 0); stA(0, 2, 0); stB(0, 0, 0); stB(0, 1, 0);
  stB(0, 2, 0); stB(0, 3, 0); stA(0, 1, 0); stA(0, 3, 0);
  asm volatile("s_waitcnt vmcnt(0)" ::: "memory");
  __builtin_amdgcn_s_barrier();

  int ntk = K >> 6;
  for (int kk = 0; kk < ntk; ++kk) {
    int d = kk & 1, e = d ^ 1, k1 = (kk + 1) << 6;
    bool pf = (kk + 1 < ntk);
    { // P1
#pragma unroll
      for (int ni = 0; ni < 2; ++ni) { Bf01[ni][0] = ldsB(d, ni, 0); Bf01[ni][1] = ldsB(d, ni, 1); }
#pragma unroll
      for (int mi = 0; mi < 4; ++mi) { Af[mi][0] = ldsA(d, mi, 0); Af[mi][1] = ldsA(d, mi, 1); }
      if (pf) { stA(e, 0, k1); stA(e, 2, k1); stB(e, 0, k1); stB(e, 1, k1); }
      PH_OPEN();
#pragma unroll
      for (int mi = 0; mi < 4; ++mi)
#pragma unroll
        for (int ni = 0; ni < 2; ++ni) {
          acc[mi][ni] = __builtin_amdgcn_mfma_f32_16x16x32_bf16(Af[mi][0], Bf01[ni][0], acc[mi][ni], 0, 0, 0);
          acc[mi][ni] = __builtin_amdgcn_mfma_f32_16x16x32_bf16(Af[mi][1], Bf01[ni][1], acc[mi][ni], 0, 0, 0);
        }
      __builtin_amdgcn_s_setprio(0);
      if (pf) { asm volatile("s_waitcnt vmcnt(6)" ::: "memory"); }
      else    { asm volatile("s_waitcnt vmcnt(2)" ::: "memory"); }
      __builtin_amdgcn_s_barrier();
    }
    { // P2
#pragma unroll
      for (int ni = 0; ni < 2; ++ni) { Bf23[ni][0] = ldsB(d, 2 + ni, 0); Bf23[ni][1] = ldsB(d, 2 + ni, 1); }
      if (pf) { stB(e, 2, k1); stB(e, 3, k1); }
      PH_OPEN();
#pragma unroll
      for (int mi = 0; mi < 4; ++mi)
#pragma unroll
        for (int ni = 0; ni < 2; ++ni) {
          acc[mi][2 + ni] = __builtin_amdgcn_mfma_f32_16x16x32_bf16(Af[mi][0], Bf23[ni][0], acc[mi][2 + ni], 0, 0, 0);
          acc[mi][2 + ni] = __builtin_amdgcn_mfma_f32_16x16x32_bf16(Af[mi][1], Bf23[ni][1], acc[mi][2 + ni], 0, 0, 0);
        }
      __builtin_amdgcn_s_setprio(0);
      if (pf) { asm volatile("s_waitcnt vmcnt(6)" ::: "memory"); }
      else    { asm volatile("s_waitcnt vmcnt(0)" ::: "memory"); }
      __builtin_amdgcn_s_barrier();
    }
    { // P3
#pragma unroll
      for (int mi = 0; mi < 4; ++mi) { Af[mi][0] = ldsA(d, 4 + mi, 0); Af[mi][1] = ldsA(d, 4 + mi, 1); }
      if (pf) { stA(e, 1, k1); stA(e, 3, k1); }
      PH_OPEN();
#pragma unroll
      for (int mi = 0; mi < 4; ++mi)
#pragma unroll
        for (int ni = 0; ni < 2; ++ni) {
          acc[4 + mi][2 + ni] = __builtin_amdgcn_mfma_f32_16x16x32_bf16(Af[mi][0], Bf23[ni][0], acc[4 + mi][2 + ni], 0, 0, 0);
          acc[4 + mi][2 + ni] = __builtin_amdgcn_mfma_f32_16x16x32_bf16(Af[mi][1], Bf23[ni][1], acc[4 + mi][2 + ni], 0, 0, 0);
        }
      __builtin_amdgcn_s_setprio(0);
      __builtin_amdgcn_s_barrier();
    }
    { // P4
      PH_OPEN();
#pragma unroll
      for (int mi = 0; mi < 4; ++mi)
#pragma unroll
        for (int ni = 0; ni < 2; ++ni) {
          acc[4 + mi][ni] = __builtin_amdgcn_mfma_f32_16x16x32_bf16(Af[mi][0], Bf01[ni][0], acc[4 + mi][ni], 0, 0, 0);
          acc[4 + mi][ni] = __builtin_amdgcn_mfma_f32_16x16x32_bf16(Af[mi][1], Bf01[ni][1], acc[4 + mi][ni], 0, 0, 0);
        }
      __builtin_amdgcn_s_setprio(0);
      if (pf) { asm volatile("s_waitcnt vmcnt(4)" ::: "memory"); }
      __builtin_amdgcn_s_barrier();
    }
  }
#undef PH_OPEN

  float* fb = (float*)sm;
  int fbase = wv * 4096;
  float bv[4];
#pragma unroll
  for (int ni = 0; ni < 4; ++ni) bv[ni] = bias[n0 + wn * 64 + ni * 16 + l15];
#pragma unroll
  for (int p = 0; p < 2; ++p) {
    if (p) { asm volatile("s_waitcnt lgkmcnt(0)" ::: "memory"); __builtin_amdgcn_sched_barrier(0); }
#pragma unroll
    for (int mi = 0; mi < 4; ++mi)
#pragma unroll
      for (int ni = 0; ni < 4; ++ni)
#pragma unroll
        for (int r = 0; r < 4; ++r)
          fb[fbase + (mi * 16 + lg * 4 + r) * 64 + ni * 16 + l15] = acc[4 * p + mi][ni][r] + bv[ni];
    asm volatile("s_waitcnt lgkmcnt(0)" ::: "memory");
    __builtin_amdgcn_sched_barrier(0);
#pragma unroll
    for (int i = 0; i < 16; ++i) {
      int row = i * 4 + lg;
      f32x4 v = *(const f32x4*)&fb[fbase + row * 64 + l15 * 4];
      int grow = m0 + wm * 128 + p * 64 + row;
      *(f32x4*)(&C[(size_t)grow * ldc + n0 + wn * 64 + l15 * 4]) = v;
    }
  }
}

// ----------------------------------------------------------------
extern "C" void kernel_launch(void* const* d_in, const int* in_sizes, int n_in,
                              void* d_out, int out_size, void* d_ws, size_t ws_size,
                              hipStream_t stream) {
  const int* x = (const int*)d_in[0];
  const float* tok = (const float*)d_in[1];
  const float* pos = (const float*)d_in[2];
  const float* wq = (const float*)d_in[3];
  const float* wk = (const float*)d_in[4];
  const float* wv = (const float*)d_in[5];
  const float* wo = (const float*)d_in[6];
  const float* bo = (const float*)d_in[7];
  const float* ln1g = (const float*)d_in[8];
  const float* ln1b = (const float*)d_in[9];
  const float* ln2g = (const float*)d_in[10];
  const float* ln2b = (const float*)d_in[11];
  const float* w1 = (const float*)d_in[12];
  const float* b1 = (const float*)d_in[13];
  const float* w2 = (const float*)d_in[14];
  const float* b2 = (const float*)d_in[15];
  const float* outw = (const float*)d_in[16];
  const float* outb = (const float*)d_in[17];
  float* out = (float*)d_out;

  const size_t MiB = 1 << 20;
  const size_t need = 4 * MiB + 65536000;
  if (ws_size < need) return;
  char* base = (char*)d_ws;
  unsigned short* hbf = (unsigned short*)base;            // 4 MiB, persistent
  char* R = base + 4 * MiB;
  float* hf  = (float*)(R);                               // 8 MiB
  float* x1f = (float*)(R + 8 * MiB);                     // 8 MiB
  unsigned short* x1bf = (unsigned short*)(R + 16 * MiB); // 4 MiB
  float* cfA = (float*)(R + 20 * MiB);                    // 8 MiB
  float* cfB = (float*)(R + 28 * MiB);                    // 8 MiB
  unsigned short* qs = (unsigned short*)(R + 36 * MiB);   // 6 slots x 4 MiB
  const size_t SL = 2048ull * 1024;
  unsigned short* qbf = qs;
  unsigned short* kbf = qs + SL;
  unsigned short* vbf = qs + 2 * SL;                      // attn-out
  unsigned short* vtbf = qs + 3 * SL;                     // vt, also wobf
  unsigned short* wobf = vtbf;
  unsigned short* w1bf = qbf;                             // slots 0-1 (8 MiB), q/k dead after attn
  unsigned short* w2bf = qbf;                             // same slots; cvt AFTER gemmF1 consumed w1
  unsigned short* ffbf = vbf;                             // slots 2-5 (16 MiB)
  unsigned short* wqbf = (unsigned short*)(R + 60 * MiB); // 3 x 16384 u16 (96 KB, layers only)
  unsigned short* wkbf = wqbf + 16384;
  unsigned short* wvbf = wkbf + 16384;
  unsigned short* outwbf = (unsigned short*)R;            // 62.5 MiB, after layers

  embed_kernel<<<2048, 256, 0, stream>>>(x, tok, pos, hf, hbf);
  cvt3q_kernel<<<24, 256, 0, stream>>>(wq, wqbf, wk, wkbf, wv, wvbf);
  for (int l = 0; l < 4; ++l) {
    qkvt_kernel<<<dim3(32, 16), 256, 0, stream>>>(hbf, wqbf + l * 4096, wkbf + l * 4096,
                                                  wvbf + l * 4096, qbf, kbf, vtbf);
    attn_kernel<<<dim3(16, 32), 256, 0, stream>>>(qbf, kbf, vtbf, vbf);
    cvt2_kernel<<<2048, 256, 0, stream>>>(wo + (size_t)l * 1048576, wobf, 131072,
                                          w1 + (size_t)l * 4194304, w1bf, 524288);
    gemmF2_kernel<<<256, 512, 81920, stream>>>(
        vbf, 1024, wobf, 1024, bo + l * 1024, cfA, cfB, 512);
    ln_kernel<<<2048, 256, 0, stream>>>(cfA, cfB, hf, ln1g + l * 1024, ln1b + l * 1024,
                                        x1f, x1bf);
    gemmF1_kernel<<<256, 512, 131072, stream>>>(
        x1bf, 1024, w1bf, 1024, b1 + l * 4096, ffbf, 4096, 1024);
    cvt_kernel<<<2048, 256, 0, stream>>>(w2 + (size_t)l * 4194304, w2bf, 524288);
    gemmF2_kernel<<<256, 512, 81920, stream>>>(
        ffbf, 4096, w2bf, 4096, b2 + l * 1024, cfA, cfB, 2048);
    ln_kernel<<<2048, 256, 0, stream>>>(cfA, cfB, x1f, ln2g + l * 1024, ln2b + l * 1024,
                                        hf, hbf);
  }
  cvt_kernel<<<2048, 256, 0, stream>>>(outw, outwbf, 4096000);
  gemm256_kernel<<<1000, 512, 131072, stream>>>(hbf, 1024, outwbf, 1024, outb, out, 32000, 1024);
}